// Round 2
// baseline (543.569 us; speedup 1.0000x reference)
//
#include <hip/hip_runtime.h>

#define HW 1024
#define CH_STRIDE (1024*1024)
#define IMG_STRIDE (3*1024*1024)

// DCT-II 8x8 matrix (matches reference _dct_matrix(8), fp64 -> fp32)
constexpr float DCM[8][8] = {
    {0.35355339059327376f, 0.35355339059327376f, 0.35355339059327376f, 0.35355339059327376f,
     0.35355339059327376f, 0.35355339059327376f, 0.35355339059327376f, 0.35355339059327376f},
    {0.49039264020161522f, 0.41573480615127262f, 0.27778511650980111f, 0.09754516100806413f,
    -0.09754516100806413f,-0.27778511650980111f,-0.41573480615127262f,-0.49039264020161522f},
    {0.46193976625564337f, 0.19134171618254489f,-0.19134171618254489f,-0.46193976625564337f,
    -0.46193976625564337f,-0.19134171618254489f, 0.19134171618254489f, 0.46193976625564337f},
    {0.41573480615127262f,-0.09754516100806413f,-0.49039264020161522f,-0.27778511650980111f,
     0.27778511650980111f, 0.49039264020161522f, 0.09754516100806413f,-0.41573480615127262f},
    {0.35355339059327376f,-0.35355339059327376f,-0.35355339059327376f, 0.35355339059327376f,
     0.35355339059327376f,-0.35355339059327376f,-0.35355339059327376f, 0.35355339059327376f},
    {0.27778511650980111f,-0.49039264020161522f, 0.09754516100806413f, 0.41573480615127262f,
    -0.41573480615127262f,-0.09754516100806413f, 0.49039264020161522f,-0.27778511650980111f},
    {0.19134171618254489f,-0.46193976625564337f, 0.46193976625564337f,-0.19134171618254489f,
    -0.19134171618254489f, 0.46193976625564337f,-0.46193976625564337f, 0.19134171618254489f},
    {0.09754516100806413f,-0.27778511650980111f, 0.41573480615127262f,-0.49039264020161522f,
     0.49039264020161522f,-0.41573480615127262f, 0.27778511650980111f,-0.09754516100806413f}
};

// band_of[flat i*8+j] = zigzag_position / 8  (matches reference _zigzag_flat(8))
constexpr int BAND[64] = {
    0,0,0,0,1,1,3,3,
    0,0,0,1,2,3,3,5,
    0,1,1,2,3,3,5,5,
    1,1,2,3,3,5,5,6,
    1,2,2,4,4,5,6,6,
    2,2,4,4,5,6,6,7,
    2,4,4,5,6,7,7,7,
    4,4,6,6,7,7,7,7
};

__device__ __forceinline__ float wave_reduce_add(float v) {
    #pragma unroll
    for (int off = 32; off > 0; off >>= 1)
        v += __shfl_xor(v, off, 64);
    return v;
}

// partials layout: [2048 wg][16] doubles; slot s<8 = band-sum, s>=8 = band-sumsq
// wgmax: [2048] floats
__global__ __launch_bounds__(256) void dct_band_kernel(
    const float* __restrict__ images,
    double* __restrict__ partials,
    float* __restrict__ wgmax)
{
    const int tid = threadIdx.x;
    const int wg = blockIdx.x;
    const int img = wg >> 6;            // 64 WGs per image
    const int chunk = wg & 63;
    const int t = chunk * 256 + tid;    // block index within image [0,16384)
    const int by = t >> 7;              // 128 blocks per row
    const int bx = t & 127;

    const float* base = images + (size_t)img * IMG_STRIDE + (size_t)(by * 8) * HW + bx * 8;

    float lum[8][8];
    float fmax_v = 0.0f;
    #pragma unroll
    for (int r = 0; r < 8; ++r) {
        const float4* pr = (const float4*)(base + (size_t)r * HW);
        const float4* pg = (const float4*)(base + CH_STRIDE + (size_t)r * HW);
        const float4* pb = (const float4*)(base + 2 * CH_STRIDE + (size_t)r * HW);
        float4 R0 = pr[0], R1 = pr[1];
        float4 G0 = pg[0], G1 = pg[1];
        float4 B0 = pb[0], B1 = pb[1];
        float rr[8] = {R0.x, R0.y, R0.z, R0.w, R1.x, R1.y, R1.z, R1.w};
        float gg[8] = {G0.x, G0.y, G0.z, G0.w, G1.x, G1.y, G1.z, G1.w};
        float bb[8] = {B0.x, B0.y, B0.z, B0.w, B1.x, B1.y, B1.z, B1.w};
        #pragma unroll
        for (int c = 0; c < 8; ++c) {
            float v = 0.299f * rr[c] + 0.587f * gg[c] + 0.114f * bb[c];
            lum[r][c] = v;
            fmax_v = fmaxf(fmax_v, v);
        }
    }

    // Stage 1: column transform  lum <- D * lum
    #pragma unroll
    for (int j = 0; j < 8; ++j) {
        float col[8];
        #pragma unroll
        for (int i = 0; i < 8; ++i) col[i] = lum[i][j];
        #pragma unroll
        for (int k = 0; k < 8; ++k) {
            float s = 0.0f;
            #pragma unroll
            for (int i = 0; i < 8; ++i) s += DCM[k][i] * col[i];
            lum[k][j] = s;
        }
    }

    // Stage 2: row transform + band accumulate  C = (D*X) * D^T
    float sband[8] = {0,0,0,0,0,0,0,0};
    float qband[8] = {0,0,0,0,0,0,0,0};
    #pragma unroll
    for (int k = 0; k < 8; ++k) {
        float row[8];
        #pragma unroll
        for (int j = 0; j < 8; ++j) row[j] = lum[k][j];
        #pragma unroll
        for (int l = 0; l < 8; ++l) {
            float s = 0.0f;
            #pragma unroll
            for (int j = 0; j < 8; ++j) s += row[j] * DCM[l][j];
            float a = fabsf(s);
            const int b = BAND[k * 8 + l];   // compile-time constant after unroll
            sband[b] += a;
            qband[b] += a * a;
        }
    }

    // Reductions: wave shuffle -> LDS cross-wave -> per-WG partial write (no atomics)
    #pragma unroll
    for (int b = 0; b < 8; ++b) {
        sband[b] = wave_reduce_add(sband[b]);
        qband[b] = wave_reduce_add(qband[b]);
    }
    #pragma unroll
    for (int off = 32; off > 0; off >>= 1)
        fmax_v = fmaxf(fmax_v, __shfl_xor(fmax_v, off, 64));

    __shared__ float lds_s[4][8];
    __shared__ float lds_q[4][8];
    __shared__ float lds_m[4];
    const int wave = tid >> 6;
    const int lane = tid & 63;
    if (lane == 0) {
        #pragma unroll
        for (int b = 0; b < 8; ++b) { lds_s[wave][b] = sband[b]; lds_q[wave][b] = qband[b]; }
        lds_m[wave] = fmax_v;
    }
    __syncthreads();
    if (tid < 8) {
        float s = lds_s[0][tid] + lds_s[1][tid] + lds_s[2][tid] + lds_s[3][tid];
        partials[wg * 16 + tid] = (double)s;
    } else if (tid < 16) {
        const int b = tid - 8;
        float q = lds_q[0][b] + lds_q[1][b] + lds_q[2][b] + lds_q[3][b];
        partials[wg * 16 + tid] = (double)q;
    } else if (tid == 16) {
        wgmax[wg] = fmaxf(fmaxf(lds_m[0], lds_m[1]), fmaxf(lds_m[2], lds_m[3]));
    }
}

__global__ __launch_bounds__(256) void finalize_kernel(
    const double* __restrict__ partials,   // [2048][16]
    const float* __restrict__ wgmax,       // [2048]
    const float* __restrict__ proj_w,      // [512][16]
    const float* __restrict__ proj_b,      // [512]
    float* __restrict__ out)               // [32][512]
{
    const int img = blockIdx.x;
    const int tid = threadIdx.x;

    // --- global max over all 2048 WG maxes ---
    float m = 0.0f;
    #pragma unroll
    for (int k = 0; k < 8; ++k) m = fmaxf(m, wgmax[tid + k * 256]);
    #pragma unroll
    for (int off = 32; off > 0; off >>= 1)
        m = fmaxf(m, __shfl_xor(m, off, 64));
    __shared__ float smax[4];
    if ((tid & 63) == 0) smax[tid >> 6] = m;

    // --- band partial reduction: stream s (0..15), 16 threads per stream ---
    const int s = tid >> 4;      // which of the 16 (sum/sumsq) streams
    const int tsub = tid & 15;
    double acc = 0.0;
    #pragma unroll
    for (int k = 0; k < 4; ++k)
        acc += partials[(size_t)(img * 64 + tsub + k * 16) * 16 + s];
    __shared__ double dred[16][17];
    dred[s][tsub] = acc;
    __syncthreads();

    __shared__ float raw[16];
    const float gmax = fmaxf(fmaxf(smax[0], smax[1]), fmaxf(smax[2], smax[3]));
    const float scale = (gmax <= 1.0f) ? 255.0f : 1.0f;

    __shared__ double totals[16];
    if (tid < 16) {
        double tot = 0.0;
        #pragma unroll
        for (int k = 0; k < 16; ++k) tot += dred[tid][k];
        totals[tid] = tot;
    }
    __syncthreads();
    if (tid < 8) {
        const double S1 = totals[tid];
        const double S2 = totals[8 + tid];
        const double N = 131072.0;   // 128*128*8 values per (img, band)
        double mean = S1 / N;
        double var = (S2 - S1 * S1 / N) / (N - 1.0);
        if (var < 0.0) var = 0.0;
        raw[tid]     = scale * (float)mean;
        raw[8 + tid] = scale * (float)sqrt(var);
    }
    __syncthreads();

    // --- projection: out[img][f] = raw . proj_w[f] + proj_b[f] ---
    #pragma unroll
    for (int o = 0; o < 2; ++o) {
        const int f = tid + o * 256;
        float accp = proj_b[f];
        #pragma unroll
        for (int r = 0; r < 16; ++r)
            accp += raw[r] * proj_w[f * 16 + r];
        out[img * 512 + f] = accp;
    }
}

extern "C" void kernel_launch(void* const* d_in, const int* in_sizes, int n_in,
                              void* d_out, int out_size, void* d_ws, size_t ws_size,
                              hipStream_t stream) {
    const float* images = (const float*)d_in[0];
    // d_in[1] (dct_matrix) and d_in[2] (zigzag_flat) are deterministic; hardcoded above.
    const float* proj_w = (const float*)d_in[3];
    const float* proj_b = (const float*)d_in[4];
    float* out = (float*)d_out;

    double* partials = (double*)d_ws;               // [2048][16] doubles = 256 KB
    float* wgmax = (float*)(partials + 2048 * 16);  // [2048] floats = 8 KB
    // Every slot is written by dct_band_kernel each call -> no zero-init needed.

    dct_band_kernel<<<2048, 256, 0, stream>>>(images, partials, wgmax);
    finalize_kernel<<<32, 256, 0, stream>>>(partials, wgmax, proj_w, proj_b, out);
}

// Round 3
// 516.244 us; speedup vs baseline: 1.0529x; 1.0529x over previous
//
#include <hip/hip_runtime.h>

#define HW 1024
#define CH_STRIDE (1024*1024)
#define IMG_STRIDE (3*1024*1024)

// DCT-II 8x8 matrix (matches reference _dct_matrix(8), fp64 -> fp32)
constexpr float DCM[8][8] = {
    {0.35355339059327376f, 0.35355339059327376f, 0.35355339059327376f, 0.35355339059327376f,
     0.35355339059327376f, 0.35355339059327376f, 0.35355339059327376f, 0.35355339059327376f},
    {0.49039264020161522f, 0.41573480615127262f, 0.27778511650980111f, 0.09754516100806413f,
    -0.09754516100806413f,-0.27778511650980111f,-0.41573480615127262f,-0.49039264020161522f},
    {0.46193976625564337f, 0.19134171618254489f,-0.19134171618254489f,-0.46193976625564337f,
    -0.46193976625564337f,-0.19134171618254489f, 0.19134171618254489f, 0.46193976625564337f},
    {0.41573480615127262f,-0.09754516100806413f,-0.49039264020161522f,-0.27778511650980111f,
     0.27778511650980111f, 0.49039264020161522f, 0.09754516100806413f,-0.41573480615127262f},
    {0.35355339059327376f,-0.35355339059327376f,-0.35355339059327376f, 0.35355339059327376f,
     0.35355339059327376f,-0.35355339059327376f,-0.35355339059327376f, 0.35355339059327376f},
    {0.27778511650980111f,-0.49039264020161522f, 0.09754516100806413f, 0.41573480615127262f,
    -0.41573480615127262f,-0.09754516100806413f, 0.49039264020161522f,-0.27778511650980111f},
    {0.19134171618254489f,-0.46193976625564337f, 0.46193976625564337f,-0.19134171618254489f,
    -0.19134171618254489f, 0.46193976625564337f,-0.46193976625564337f, 0.19134171618254489f},
    {0.09754516100806413f,-0.27778511650980111f, 0.41573480615127262f,-0.49039264020161522f,
     0.49039264020161522f,-0.41573480615127262f, 0.27778511650980111f,-0.09754516100806413f}
};

// band_of[flat i*8+j] = zigzag_position / 8  (matches reference _zigzag_flat(8))
constexpr int BAND[64] = {
    0,0,0,0,1,1,3,3,
    0,0,0,1,2,3,3,5,
    0,1,1,2,3,3,5,5,
    1,1,2,3,3,5,5,6,
    1,2,2,4,4,5,6,6,
    2,2,4,4,5,6,6,7,
    2,4,4,5,6,7,7,7,
    4,4,6,6,7,7,7,7
};

__device__ __forceinline__ float wave_reduce_add(float v) {
    #pragma unroll
    for (int off = 32; off > 0; off >>= 1)
        v += __shfl_xor(v, off, 64);
    return v;
}

// async global->LDS, 16B per lane; lds base must be wave-uniform (HW adds lane*16)
#define GLOAD_LDS16(g, l)                                                              \
    __builtin_amdgcn_global_load_lds((const __attribute__((address_space(1))) void*)(g), \
                                     (__attribute__((address_space(3))) void*)(l),       \
                                     16, 0, 0)

template<int VM>
__device__ __forceinline__ void wait_vm_barrier() {
    asm volatile("s_waitcnt vmcnt(%0)\n\ts_barrier" :: "i"(VM) : "memory");
}
__device__ __forceinline__ void plain_barrier() {
    asm volatile("s_waitcnt lgkmcnt(0)\n\ts_barrier" ::: "memory");
}

// WG = 256 threads = 2 block-rows x 128 block-cols of one image (image rows [by0*8, by0*8+16)).
// Chunk c (c=0..7) = image rows {by0*8+c, by0*8+8+c} x 3 channels = 6 segments x 4KB = 24KB.
// Thread t folds row c of its own 8x8 block on arrival: S[k][j] += DCM[k][c]*lum[j].
__global__ __launch_bounds__(256) void dct_band_kernel(
    const float* __restrict__ images,
    double* __restrict__ partials,   // [2048][16]
    float* __restrict__ wgmax)       // [2048]
{
    __shared__ __align__(16) float smem[2][6 * 1024];   // 2 x 24KB double buffer

    const int tid = threadIdx.x;
    const int wg = blockIdx.x;
    const int img = wg >> 6;            // 64 WGs per image
    const int pair = wg & 63;
    const int row0 = pair * 16;         // first image row of this WG's tile
    const int h = tid >> 7;             // which of the 2 block-rows this thread's block is in
    const int bx = tid & 127;

    const float* img_base = images + (size_t)img * IMG_STRIDE;
    const int wave_u = (tid >> 6) * 256;   // wave-uniform LDS float offset (1KB per wave)

    float S[8][8];
    #pragma unroll
    for (int k = 0; k < 8; ++k)
        #pragma unroll
        for (int j = 0; j < 8; ++j) S[k][j] = 0.0f;
    float fmax_v = 0.0f;

    auto issue_chunk = [&](int c, int p) {
        #pragma unroll
        for (int ch = 0; ch < 3; ++ch) {
            #pragma unroll
            for (int hh = 0; hh < 2; ++hh) {
                const float* g = img_base + (size_t)ch * CH_STRIDE
                               + (size_t)(row0 + hh * 8 + c) * HW + tid * 4;
                float* l = &smem[p][(ch * 2 + hh) * 1024 + wave_u];
                GLOAD_LDS16(g, l);
            }
        }
    };

    auto fold_chunk = [&](int c, int p) {
        const int o = bx * 8;
        float4 r0 = *(const float4*)&smem[p][(0 * 2 + h) * 1024 + o];
        float4 r1 = *(const float4*)&smem[p][(0 * 2 + h) * 1024 + o + 4];
        float4 g0 = *(const float4*)&smem[p][(1 * 2 + h) * 1024 + o];
        float4 g1 = *(const float4*)&smem[p][(1 * 2 + h) * 1024 + o + 4];
        float4 b0 = *(const float4*)&smem[p][(2 * 2 + h) * 1024 + o];
        float4 b1 = *(const float4*)&smem[p][(2 * 2 + h) * 1024 + o + 4];
        float rr[8] = {r0.x, r0.y, r0.z, r0.w, r1.x, r1.y, r1.z, r1.w};
        float gg[8] = {g0.x, g0.y, g0.z, g0.w, g1.x, g1.y, g1.z, g1.w};
        float bb[8] = {b0.x, b0.y, b0.z, b0.w, b1.x, b1.y, b1.z, b1.w};
        float lum[8];
        #pragma unroll
        for (int j = 0; j < 8; ++j) {
            float v = 0.299f * rr[j] + 0.587f * gg[j] + 0.114f * bb[j];
            lum[j] = v;
            fmax_v = fmaxf(fmax_v, v);
        }
        #pragma unroll
        for (int k = 0; k < 8; ++k)
            #pragma unroll
            for (int j = 0; j < 8; ++j)
                S[k][j] += DCM[k][c] * lum[j];   // DCM[k][c] is a compile-time constant
    };

    issue_chunk(0, 0);
    #define STEP(c, VMW)                                   \
        plain_barrier();                                   \
        if ((c) + 1 < 8) issue_chunk((c) + 1, ((c) + 1) & 1); \
        wait_vm_barrier<VMW>();                            \
        fold_chunk((c), (c) & 1);
    STEP(0, 6) STEP(1, 6) STEP(2, 6) STEP(3, 6)
    STEP(4, 6) STEP(5, 6) STEP(6, 6) STEP(7, 0)
    #undef STEP

    // Stage 2: row transform + band accumulate  C = S * D^T
    float sband[8] = {0,0,0,0,0,0,0,0};
    float qband[8] = {0,0,0,0,0,0,0,0};
    #pragma unroll
    for (int k = 0; k < 8; ++k) {
        #pragma unroll
        for (int l = 0; l < 8; ++l) {
            float s = 0.0f;
            #pragma unroll
            for (int j = 0; j < 8; ++j) s += S[k][j] * DCM[l][j];
            float a = fabsf(s);
            const int b = BAND[k * 8 + l];
            sband[b] += a;
            qband[b] += a * a;
        }
    }

    // Reductions: wave shuffle -> LDS cross-wave -> per-WG partial write (no atomics)
    #pragma unroll
    for (int b = 0; b < 8; ++b) {
        sband[b] = wave_reduce_add(sband[b]);
        qband[b] = wave_reduce_add(qband[b]);
    }
    #pragma unroll
    for (int off = 32; off > 0; off >>= 1)
        fmax_v = fmaxf(fmax_v, __shfl_xor(fmax_v, off, 64));

    __shared__ float lds_s[4][8];
    __shared__ float lds_q[4][8];
    __shared__ float lds_m[4];
    const int wave = tid >> 6;
    const int lane = tid & 63;
    if (lane == 0) {
        #pragma unroll
        for (int b = 0; b < 8; ++b) { lds_s[wave][b] = sband[b]; lds_q[wave][b] = qband[b]; }
        lds_m[wave] = fmax_v;
    }
    __syncthreads();
    if (tid < 8) {
        float s = lds_s[0][tid] + lds_s[1][tid] + lds_s[2][tid] + lds_s[3][tid];
        partials[wg * 16 + tid] = (double)s;
    } else if (tid < 16) {
        const int b = tid - 8;
        float q = lds_q[0][b] + lds_q[1][b] + lds_q[2][b] + lds_q[3][b];
        partials[wg * 16 + tid] = (double)q;
    } else if (tid == 16) {
        wgmax[wg] = fmaxf(fmaxf(lds_m[0], lds_m[1]), fmaxf(lds_m[2], lds_m[3]));
    }
}

__global__ __launch_bounds__(256) void finalize_kernel(
    const double* __restrict__ partials,   // [2048][16]
    const float* __restrict__ wgmax,       // [2048]
    const float* __restrict__ proj_w,      // [512][16]
    const float* __restrict__ proj_b,      // [512]
    float* __restrict__ out)               // [32][512]
{
    const int img = blockIdx.x;
    const int tid = threadIdx.x;

    float m = 0.0f;
    #pragma unroll
    for (int k = 0; k < 8; ++k) m = fmaxf(m, wgmax[tid + k * 256]);
    #pragma unroll
    for (int off = 32; off > 0; off >>= 1)
        m = fmaxf(m, __shfl_xor(m, off, 64));
    __shared__ float smax[4];
    if ((tid & 63) == 0) smax[tid >> 6] = m;

    const int s = tid >> 4;
    const int tsub = tid & 15;
    double acc = 0.0;
    #pragma unroll
    for (int k = 0; k < 4; ++k)
        acc += partials[(size_t)(img * 64 + tsub + k * 16) * 16 + s];
    __shared__ double dred[16][17];
    dred[s][tsub] = acc;
    __syncthreads();

    __shared__ float raw[16];
    const float gmax = fmaxf(fmaxf(smax[0], smax[1]), fmaxf(smax[2], smax[3]));
    const float scale = (gmax <= 1.0f) ? 255.0f : 1.0f;

    __shared__ double totals[16];
    if (tid < 16) {
        double tot = 0.0;
        #pragma unroll
        for (int k = 0; k < 16; ++k) tot += dred[tid][k];
        totals[tid] = tot;
    }
    __syncthreads();
    if (tid < 8) {
        const double S1 = totals[tid];
        const double S2 = totals[8 + tid];
        const double N = 131072.0;   // 128*128*8 values per (img, band)
        double mean = S1 / N;
        double var = (S2 - S1 * S1 / N) / (N - 1.0);
        if (var < 0.0) var = 0.0;
        raw[tid]     = scale * (float)mean;
        raw[8 + tid] = scale * (float)sqrt(var);
    }
    __syncthreads();

    #pragma unroll
    for (int o = 0; o < 2; ++o) {
        const int f = tid + o * 256;
        float accp = proj_b[f];
        #pragma unroll
        for (int r = 0; r < 16; ++r)
            accp += raw[r] * proj_w[f * 16 + r];
        out[img * 512 + f] = accp;
    }
}

extern "C" void kernel_launch(void* const* d_in, const int* in_sizes, int n_in,
                              void* d_out, int out_size, void* d_ws, size_t ws_size,
                              hipStream_t stream) {
    const float* images = (const float*)d_in[0];
    // d_in[1] (dct_matrix) and d_in[2] (zigzag_flat) are deterministic; hardcoded above.
    const float* proj_w = (const float*)d_in[3];
    const float* proj_b = (const float*)d_in[4];
    float* out = (float*)d_out;

    double* partials = (double*)d_ws;               // [2048][16] doubles = 256 KB
    float* wgmax = (float*)(partials + 2048 * 16);  // [2048] floats = 8 KB
    // Every slot is written every call -> no zero-init needed.

    dct_band_kernel<<<2048, 256, 0, stream>>>(images, partials, wgmax);
    finalize_kernel<<<32, 256, 0, stream>>>(partials, wgmax, proj_w, proj_b, out);
}